// Round 2
// 94.041 us; speedup vs baseline: 1.0115x; 1.0115x over previous
//
#include <hip/hip_runtime.h>

typedef _Float16 half2v __attribute__((ext_vector_type(2)));
typedef _Float16 half8  __attribute__((ext_vector_type(8)));
typedef float    floatx4 __attribute__((ext_vector_type(4)));

#define M_DIM 64
#define K_DIM 8192
#define N_DIM 8192
#define NT 128              // cols per block (4 col-waves x 32)
#define KSB 4               // k-chunks; chunk = 2048 k = 4 ksub x 4 rounds x 128 k
// grid = (8192/NT=64) x KSB=4 = 256 blocks x 1024 thr = 1 block/CU, 16 waves
//      = 4 col-waves x 4-way in-block k-split (LDS tree) -> fp32 atomic out.
// vs r7 (KSB=16 + fp16 partial + reduce kernel): removes the 3rd dispatch +
// its gap + 32 MB partial W/R; global split-k depth 16 -> 4 (2.1M atomics).
// Timed-window model: 2 x 43.2us ws-poison fills (harness, 256MiB each,
// usage-independent) + kernels. Only the kernel portion (~8.7us) is ours.
// (Round-1 resubmit: container infra failure, source audited & unchanged.)

// x fp32 [64][8192] -> xp fp16 tiled [k/32][mt:4][lane:64][j:8]
// j-order within each 8 is sigma=(0,4,1,5,2,6,3,7) matching B nibble unpack.
__global__ __launch_bounds__(256) void permute_x_kernel(
        const float* __restrict__ x, _Float16* __restrict__ xp,
        float* __restrict__ out) {
    const int t  = blockIdx.x * 256 + threadIdx.x;
    const int c  = t & 15;
    const int q  = (t >> 4) & 3;
    const int mt = (t >> 6) & 3;
    const int kb = t >> 8;
    const int m  = mt * 16 + c;
    const int k0 = kb * 32 + q * 8;
    const float* src = x + (size_t)m * K_DIM + k0;
    float4 a = *(const float4*)(src);
    float4 b = *(const float4*)(src + 4);
    union { _Float16 h[8]; float4 f; } u;
    u.h[0] = (_Float16)a.x; u.h[1] = (_Float16)b.x;
    u.h[2] = (_Float16)a.y; u.h[3] = (_Float16)b.y;
    u.h[4] = (_Float16)a.z; u.h[5] = (_Float16)b.z;
    u.h[6] = (_Float16)a.w; u.h[7] = (_Float16)b.w;
    *(float4*)(xp + (size_t)t * 8) = u.f;
    // zero fp32 out for the atomic epilogue (harness poisons it); 65536 thr x 8
    // floats == 64*8192 exactly. permute completes before machete (same stream).
    const float4 z = {0.f, 0.f, 0.f, 0.f};
    float* o = out + (size_t)t * 8;
    *(float4*)(o)     = z;
    *(float4*)(o + 4) = z;
}

__device__ __forceinline__ void dma16(const void* g, void* l) {
    __builtin_amdgcn_global_load_lds(
        (const __attribute__((address_space(1))) unsigned int*)(uintptr_t)g,
        (__attribute__((address_space(3))) unsigned int*)(uintptr_t)l,
        16, 0, 0);
}

__device__ __forceinline__ half2v dq_pair(unsigned int bits, half2v sub, half2v sc) {
    union { unsigned int u; half2v h; } cv;
    cv.u = bits;
    return (cv.h - sub) * sc;      // v_pk_add_f16 + v_pk_mul_f16
}

__global__ __launch_bounds__(1024, 4) void machete_mm_kernel(
        const _Float16* __restrict__ xp,
        const unsigned int* __restrict__ Bq,
        const float* __restrict__ s,
        float* __restrict__ out) {
    __shared__ char astage[2][65536];                // 128 KB: 4 ksub x 16 KB, dbuf

    const int tid  = threadIdx.x;
    const int w    = tid >> 6;                       // wave 0..15
    const int lane = tid & 63;
    const int c    = lane & 15;
    const int q    = lane >> 4;
    const int cw   = w & 3;                          // col-wave 0..3 (32 cols each)
    const int ks   = w >> 2;                         // in-block k-split 0..3
    const int ns   = blockIdx.x;                     // n-strip 0..63
    const int kb   = blockIdx.y;                     // k-chunk 0..3 (2048 k each)
    const int wc   = ns * NT + cw * 32;

    // Scales: group == 128 k == one round of this wave's k-slice.
    half2v s2[4][2];
    #pragma unroll
    for (int g = 0; g < 4; ++g) {
        const size_t row = (size_t)(kb * 16 + ks * 4 + g) * N_DIM;
        const float f0 = s[row + wc + c];
        const float f1 = s[row + wc + 16 + c];
        s2[g][0] = (half2v){ (_Float16)f0, (_Float16)f0 };
        s2[g][1] = (half2v){ (_Float16)f1, (_Float16)f1 };
    }
    const half2v c1032 = { (_Float16)1032.0f, (_Float16)1032.0f };

    // A: wave's k-slice = k32-blocks [kb*64 + ks*16, +16), 4096 B per k32-block
    const char* a_base = (const char*)xp + (size_t)(kb * 64 + ks * 16) * 4096;
    // B: packed rows for this wave's slice
    const unsigned int* b_base = Bq + (size_t)(kb * 256 + ks * 64) * N_DIM + wc + c;

    auto bload = [&](int r, int d, int t) {
        return b_base[(size_t)(r * 16 + d * 4 + q) * N_DIM + 16 * t];
    };
    auto stage_dma = [&](int r, int p) {   // wave copies k32-block cw of its ksub (4 KB)
        const char* src = a_base + (size_t)(r * 4 + cw) * 4096 + lane * 16;
        char* dst = &astage[p][ks * 16384 + cw * 4096];
        #pragma unroll
        for (int i = 0; i < 4; ++i)
            dma16(src + i * 1024, dst + i * 1024);   // LDS dst wave-uniform + lane*16
    };

    floatx4 acc[4][2];
    #pragma unroll
    for (int i = 0; i < 4; ++i) { acc[i][0] = (floatx4)0.0f; acc[i][1] = (floatx4)0.0f; }

    unsigned int bcur[2][4], bnxt[2][4];
    #pragma unroll
    for (int d = 0; d < 4; ++d) { bcur[0][d] = bload(0, d, 0); bcur[1][d] = bload(0, d, 1); }
    stage_dma(0, 0);
    __syncthreads();                                 // drains DMA(0)

    #pragma unroll
    for (int r = 0; r < 4; ++r) {                    // rounds of 128 k per ksub
        const int p = r & 1;
        if (r < 3) {
            #pragma unroll
            for (int d = 0; d < 4; ++d) {
                bnxt[0][d] = bload(r + 1, d, 0);
                bnxt[1][d] = bload(r + 1, d, 1);
            }
            stage_dma(r + 1, p ^ 1);
        }

        #pragma unroll
        for (int d = 0; d < 4; ++d) {                // k32 steps in round
            half8 afr[4];
            #pragma unroll
            for (int mt = 0; mt < 4; ++mt)
                afr[mt] = *(const half8*)(
                    &astage[p][ks * 16384 + (d * 4 + mt) * 1024 + lane * 16]);
            #pragma unroll
            for (int t = 0; t < 2; ++t) {
                const unsigned int wd = bcur[t][d];
                const half2v sc = s2[r][t];
                union { half2v h2[4]; half8 h8; } b8;
                b8.h2[0] = dq_pair(( wd        & 0x000F000Fu) | 0x64006400u, c1032, sc);
                b8.h2[1] = dq_pair(((wd >> 4)  & 0x000F000Fu) | 0x64006400u, c1032, sc);
                b8.h2[2] = dq_pair(((wd >> 8)  & 0x000F000Fu) | 0x64006400u, c1032, sc);
                b8.h2[3] = dq_pair(((wd >> 12) & 0x000F000Fu) | 0x64006400u, c1032, sc);
                #pragma unroll
                for (int mt = 0; mt < 4; ++mt)
                    acc[mt][t] = __builtin_amdgcn_mfma_f32_16x16x32_f16(
                        afr[mt], b8.h8, acc[mt][t], 0, 0, 0);
            }
        }
        __syncthreads();                             // DMA(r+1) complete
        #pragma unroll
        for (int d = 0; d < 4; ++d) { bcur[0][d] = bnxt[0][d]; bcur[1][d] = bnxt[1][d]; }
    }

    // In-block 4-way k reduction via LDS tree (reuse astage; all waves synced).
    // Slot layout: slot*2048 + idx*64 + lane -> conflict-free ds ops.
    float* red = (float*)astage;
    auto spill = [&](int slot) {
        float* b = red + (size_t)slot * 2048 + lane;
        #pragma unroll
        for (int mt = 0; mt < 4; ++mt)
            #pragma unroll
            for (int t = 0; t < 2; ++t)
                #pragma unroll
                for (int rr = 0; rr < 4; ++rr)
                    b[(mt * 8 + t * 4 + rr) * 64] = acc[mt][t][rr];
    };
    auto gather = [&](int slot) {
        const float* b = red + (size_t)slot * 2048 + lane;
        #pragma unroll
        for (int mt = 0; mt < 4; ++mt)
            #pragma unroll
            for (int t = 0; t < 2; ++t)
                #pragma unroll
                for (int rr = 0; rr < 4; ++rr)
                    acc[mt][t][rr] += b[(mt * 8 + t * 4 + rr) * 64];
    };
    if (ks >= 2) spill(w - 8);                       // waves 8..15 -> slots 0..7
    __syncthreads();
    if (ks < 2) gather(w);                           // wave w += wave w+8 (same cw)
    __syncthreads();
    if (ks == 1) spill(w - 4);                       // waves 4..7 -> slots 0..3
    __syncthreads();
    if (ks == 0) {
        gather(w);                                   // full 2048-k chunk sum
        // Cross-block combine (4 kb-chunks) via native fp32 atomics; out zeroed
        // by permute_x. 64 blocks x 8192 elems x 4 = 2.1M atomic dwords total.
        #pragma unroll
        for (int mt = 0; mt < 4; ++mt)
            #pragma unroll
            for (int t = 0; t < 2; ++t)
                #pragma unroll
                for (int rr = 0; rr < 4; ++rr) {
                    const int m = mt * 16 + q * 4 + rr;
                    unsafeAtomicAdd(out + (size_t)m * N_DIM + wc + 16 * t + c,
                                    acc[mt][t][rr]);
                }
    }
}

extern "C" void kernel_launch(void* const* d_in, const int* in_sizes, int n_in,
                              void* d_out, int out_size, void* d_ws, size_t ws_size,
                              hipStream_t stream) {
    const float*        x  = (const float*)d_in[0];
    const unsigned int* Bq = (const unsigned int*)d_in[1];
    const float*        sc = (const float*)d_in[2];
    float* out   = (float*)d_out;
    _Float16* xp = (_Float16*)d_ws;                  // 1 MB (only ws use now)

    permute_x_kernel<<<dim3(M_DIM * K_DIM / 8 / 256), 256, 0, stream>>>(x, xp, out);
    machete_mm_kernel<<<dim3(N_DIM / NT, KSB), 1024, 0, stream>>>(xp, Bq, sc, out);
}